// Round 6
// baseline (234.639 us; speedup 1.0000x reference)
//
#include <hip/hip_runtime.h>

// SoftEmbeddedDecisionRules: balanced binary hierarchy over C=1024 classes.
// out[b,c] = prod over 10 levels of softmax-over-2-children prob of the branch
// containing c; child logit = mean of raw logits over the child's block;
// softmax over 2 == sigmoid(diff of means).
//
// R6: R5's quarter-interleaved wave-per-row math, but 4 ROWS PER WAVE with a
// depth-2 software pipeline (two named register buffers, no runtime indexing):
// loads for row i+1 issue BEFORE row i's compute, so HBM latency hides under
// the previous row's sigmoid/butterfly chain and stores overlap next loads.
// R4 vs R5 proved access pattern & sigmoid count don't matter (both 82us,
// 31% HBM, all pipes idle) -> theory: per-wave load->drain->compute->die
// serialization. This attacks exactly that. ZERO barriers, ZERO LDS.

#define C 1024
#define ROWS_PER_WAVE 4

__device__ __forceinline__ float sigmoid_of(float x) {
    // 1 / (1 + exp(x)); v_rcp_f32 approx (~1e-7 rel err, absmax budget 3e-5)
    return __builtin_amdgcn_rcpf(1.0f + __expf(x));
}

__device__ __forceinline__ void load_row(const float* __restrict__ rowp, int lane,
                                         float4& q0, float4& q1, float4& q2, float4& q3) {
    // 4 independent, per-instruction-contiguous 1KiB wave loads
    q0 = ((const float4*)(rowp +   0))[lane];
    q1 = ((const float4*)(rowp + 256))[lane];
    q2 = ((const float4*)(rowp + 512))[lane];
    q3 = ((const float4*)(rowp + 768))[lane];
}

__device__ __forceinline__ void process_row(const float4 L0, const float4 L1,
                                            const float4 L2, const float4 L3,
                                            float* __restrict__ orow, int lane) {
    const float4 L[4] = {L0, L1, L2, L3};
    float pA[4], pB[4], p2[4], sum[4], com[4];
#pragma unroll
    for (int q = 0; q < 4; ++q) {
        const float s2a = L[q].x + L[q].y;
        const float s2b = L[q].z + L[q].w;
        pA[q]  = sigmoid_of(L[q].y - L[q].x);          // seg=1: p(even class)
        pB[q]  = sigmoid_of(L[q].w - L[q].z);
        p2[q]  = sigmoid_of((s2b - s2a) * 0.5f);       // seg=2: p(left pair)
        sum[q] = s2a + s2b;                            // lane's 4-class block sum
        com[q] = 1.0f;
    }

    // levels seg=4..128: 6-step butterfly over lanes, 4 quarters interleaved
    float inv_seg = 0.25f;
#pragma unroll
    for (int k = 1; k <= 32; k <<= 1) {
        float pr[4];
#pragma unroll
        for (int q = 0; q < 4; ++q) pr[q] = __shfl_xor(sum[q], k, 64);
#pragma unroll
        for (int q = 0; q < 4; ++q) {
            com[q] *= sigmoid_of((pr[q] - sum[q]) * inv_seg);
            sum[q] += pr[q];
        }
        inv_seg *= 0.5f;
    }

    // top two levels (seg=256, seg=512), lane-local on quarter totals
    const float pRoot = sigmoid_of((sum[2] + sum[3] - sum[0] - sum[1]) * (1.0f / 512.0f));
    const float pL    = sigmoid_of((sum[1] - sum[0]) * (1.0f / 256.0f));
    const float pR    = sigmoid_of((sum[3] - sum[2]) * (1.0f / 256.0f));
    float t[4];
    t[0] = pRoot * pL;          t[1] = pRoot - t[0];
    const float rRoot = 1.0f - pRoot;
    t[2] = rRoot * pR;          t[3] = rRoot - t[2];

    // downsweep + 4 contiguous 1KiB wave stores (fire-and-forget)
#pragma unroll
    for (int q = 0; q < 4; ++q) {
        const float base = t[q] * com[q];
        const float cl = base * p2[q];
        const float cr = base - cl;
        float4 o;
        o.x = cl * pA[q];
        o.y = cl - o.x;
        o.z = cr * pB[q];
        o.w = cr - o.z;
        ((float4*)(orow + q * 256))[lane] = o;
    }
}

__global__ __launch_bounds__(256) void hier_softmax_kernel(
    const float* __restrict__ in, float* __restrict__ out) {
    const int lane = threadIdx.x & 63;
    const int gw   = blockIdx.x * 4 + (threadIdx.x >> 6);  // global wave id
    const size_t r0 = (size_t)gw * ROWS_PER_WAVE;

    const float* ip = in  + r0 * C;
    float*       op = out + r0 * C;

    float4 a0, a1, a2, a3;   // buffer A
    float4 b0, b1, b2, b3;   // buffer B

    // depth-2 pipeline: next row's loads in flight during current row's compute
    load_row(ip + 0 * C, lane, a0, a1, a2, a3);
    load_row(ip + 1 * C, lane, b0, b1, b2, b3);
    process_row(a0, a1, a2, a3, op + 0 * C, lane);
    load_row(ip + 2 * C, lane, a0, a1, a2, a3);
    process_row(b0, b1, b2, b3, op + 1 * C, lane);
    load_row(ip + 3 * C, lane, b0, b1, b2, b3);
    process_row(a0, a1, a2, a3, op + 2 * C, lane);
    process_row(b0, b1, b2, b3, op + 3 * C, lane);
}

extern "C" void kernel_launch(void* const* d_in, const int* in_sizes, int n_in,
                              void* d_out, int out_size, void* d_ws, size_t ws_size,
                              hipStream_t stream) {
    const float* in = (const float*)d_in[0];
    float* out = (float*)d_out;
    const int B = in_sizes[0] / C;                   // 32768 rows
    const int blocks = B / (4 * ROWS_PER_WAVE);      // 4 waves/block, 4 rows/wave
    hier_softmax_kernel<<<blocks, 256, 0, stream>>>(in, out);
}